// Round 2
// baseline (570.526 us; speedup 1.0000x reference)
//
#include <hip/hip_runtime.h>

// SwitchboxElement: B=65536 rows, S=10 stages, L=1023 inputs/row.
// JAX threefry RNG, partitionable=True semantics (JAX >= 0.4.36 default):
//   split(key,n)[i] = both words of threefry2x32(key, hi=0, lo=i)
//   random_bits(key, 32, shape)[f] = out0 ^ out1 of threefry2x32(key, 0, f)
// (the XOR fold is the partitionable 32-bit path; 64-bit concatenates).
// Fallback if absmax ~0.09 again: original (non-partitionable) counters.

#define NROWS 65536
#define WPB 4   // waves per block (256 threads)

struct U2 { unsigned x, y; };

__host__ __device__ constexpr unsigned rotl32(unsigned v, int r) {
  return (v << r) | (v >> (32 - r));
}

// Threefry-2x32, 20 rounds, exactly JAX's schedule.
__host__ __device__ constexpr U2 threefry2x32(unsigned k0, unsigned k1,
                                              unsigned x0, unsigned x1) {
  const unsigned ks2 = k0 ^ k1 ^ 0x1BD11BDAu;
  x0 += k0; x1 += k1;
  x0 += x1; x1 = rotl32(x1, 13); x1 ^= x0;
  x0 += x1; x1 = rotl32(x1, 15); x1 ^= x0;
  x0 += x1; x1 = rotl32(x1, 26); x1 ^= x0;
  x0 += x1; x1 = rotl32(x1, 6);  x1 ^= x0;
  x0 += k1; x1 += ks2 + 1u;
  x0 += x1; x1 = rotl32(x1, 17); x1 ^= x0;
  x0 += x1; x1 = rotl32(x1, 29); x1 ^= x0;
  x0 += x1; x1 = rotl32(x1, 16); x1 ^= x0;
  x0 += x1; x1 = rotl32(x1, 24); x1 ^= x0;
  x0 += ks2; x1 += k0 + 2u;
  x0 += x1; x1 = rotl32(x1, 13); x1 ^= x0;
  x0 += x1; x1 = rotl32(x1, 15); x1 ^= x0;
  x0 += x1; x1 = rotl32(x1, 26); x1 ^= x0;
  x0 += x1; x1 = rotl32(x1, 6);  x1 ^= x0;
  x0 += k0; x1 += k1 + 3u;
  x0 += x1; x1 = rotl32(x1, 17); x1 ^= x0;
  x0 += x1; x1 = rotl32(x1, 29); x1 ^= x0;
  x0 += x1; x1 = rotl32(x1, 16); x1 ^= x0;
  x0 += x1; x1 = rotl32(x1, 24); x1 ^= x0;
  x0 += k1; x1 += ks2 + 4u;
  x0 += x1; x1 = rotl32(x1, 13); x1 ^= x0;
  x0 += x1; x1 = rotl32(x1, 15); x1 ^= x0;
  x0 += x1; x1 = rotl32(x1, 26); x1 ^= x0;
  x0 += x1; x1 = rotl32(x1, 6);  x1 ^= x0;
  x0 += ks2; x1 += k0 + 5u;
  return U2{x0, x1};
}

// keys = jax.random.split(jax.random.key(42), 11), partitionable (fold-like):
// keys[i] = threefry2x32((0,42), x0=0, x1=i) -> (out0, out1), NO xor.
struct KeyTab { unsigned a[11]; unsigned b[11]; };
__host__ __device__ constexpr KeyTab make_keys() {
  KeyTab t{};
  for (int i = 0; i < 11; ++i) {
    U2 r = threefry2x32(0u, 42u, 0u, (unsigned)i);
    t.a[i] = r.x; t.b[i] = r.y;
  }
  return t;
}
__constant__ KeyTab g_keys = make_keys();

// 32-bit random bits at flat index f, partitionable path: out0 ^ out1.
__device__ inline unsigned jax_random_bits32(unsigned k0, unsigned k1, unsigned f) {
  U2 r = threefry2x32(k0, k1, 0u, f);
  return r.x ^ r.y;
}

// bits -> uniform[-1+eps, 1) -> sqrt(2)*erfinv (Giles single-precision, as XLA)
__device__ inline float jax_normal_from_bits(unsigned bits) {
  const float lo = -0.99999994f;  // nextafter(-1, 0)
  float f = __uint_as_float((bits >> 9) | 0x3F800000u) - 1.0f;  // [0,1)
  float u = fmaxf(lo, fmaf(f, 2.0f, lo));  // (maxval-minval) rounds to 2.0f

  float x2 = u * u;
  float oz = 1.0f - x2;            // 1 + z, z = -x2
  float lg = __logf(oz);
  float zz = -x2;
  // accurate log1p(z): lg * z / (oz - 1) unless oz == 1
  float l1p = (oz == 1.0f) ? zz : lg * (zz / (oz - 1.0f));
  float wv = -l1p;

  float p_small, p_big;
  {
    float w = wv - 2.5f;
    float p = 2.81022636e-08f;
    p = fmaf(p, w, 3.43273939e-07f);
    p = fmaf(p, w, -3.5233877e-06f);
    p = fmaf(p, w, -4.39150654e-06f);
    p = fmaf(p, w, 0.00021858087f);
    p = fmaf(p, w, -0.00125372503f);
    p = fmaf(p, w, -0.00417768164f);
    p = fmaf(p, w, 0.246640727f);
    p = fmaf(p, w, 1.50140941f);
    p_small = p;
  }
  {
    float w = __fsqrt_rn(wv) - 3.0f;
    float p = -0.000200214257f;
    p = fmaf(p, w, 0.000100950558f);
    p = fmaf(p, w, 0.00134934322f);
    p = fmaf(p, w, -0.00367342844f);
    p = fmaf(p, w, 0.00573950773f);
    p = fmaf(p, w, -0.0076224613f);
    p = fmaf(p, w, 0.00943887047f);
    p = fmaf(p, w, 1.00167406f);
    p = fmaf(p, w, 2.83297682f);
    p_big = p;
  }
  float pe = (wv < 5.0f) ? p_small : p_big;
  return 1.41421356f * (pe * u);   // sqrt(2) * (p * x), XLA order
}

__global__ __launch_bounds__(64 * WPB) void switchbox_kernel(
    const float* __restrict__ x,
    const float* __restrict__ selw,
    const float* __restrict__ constw,
    float* __restrict__ out) {
  __shared__ __align__(16) float buf[WPB][1024];
  const int w = threadIdx.x >> 6;
  const int lane = threadIdx.x & 63;
  const int row = blockIdx.x * WPB + w;

  float* b = buf[w];
  const float* xr = x + (size_t)row * 1023;

  // stage leaves into LDS (coalesced dword loads, 16 iters)
  for (int k = lane; k < 1023; k += 64) b[k] = xr[k];

  // noisy trained const -> leaf 1023 (normal(keys[10], (B,)) at flat idx=row)
  {
    float cw = constw[0];
    float om = 1.0f - fabsf(cw);
    float n = jax_normal_from_bits(
        jax_random_bits32(g_keys.a[10], g_keys.b[10], (unsigned)row));
    float c = cw + om * om * n * 0.125f;   // ref assoc: ((om^2)*n)*scale
    if (lane == 0) b[1023] = c;
  }

  // 10 halving mux stages, in place.
  for (int sel = 0; sel < 10; ++sel) {
    const int M = 512 >> sel;
    const float pw = selw[sel];
    const float om = 1.0f - fabsf(pw);
    const unsigned ka = g_keys.a[sel], kb = g_keys.b[sel];
    const unsigned base = (unsigned)row * (unsigned)M;
    for (int j = lane; j < M; j += 64) {
      unsigned f = base + (unsigned)j;           // flat idx into (B, M)
      float n = jax_normal_from_bits(jax_random_bits32(ka, kb, f));
      float s = pw + om * om * n * 0.125f;
      float2 ab = *(const float2*)&b[2 * j];     // ds_read_b64, 2-way = free
      float a = ab.x, bb = ab.y;
      b[j] = 0.5f * (s * a - s * bb + a + bb);   // ref op order
    }
    // no barrier needed: wave-private LDS region, reads precede overlapping
    // writes in wave program order; cross-iteration ranges are disjoint.
  }

  if (lane == 0) out[row] = b[0];
}

extern "C" void kernel_launch(void* const* d_in, const int* in_sizes, int n_in,
                              void* d_out, int out_size, void* d_ws, size_t ws_size,
                              hipStream_t stream) {
  (void)in_sizes; (void)n_in; (void)d_ws; (void)ws_size; (void)out_size;
  const float* x     = (const float*)d_in[0];
  const float* selw  = (const float*)d_in[1];
  const float* constw= (const float*)d_in[2];
  float* out = (float*)d_out;
  switchbox_kernel<<<dim3(NROWS / WPB), dim3(64 * WPB), 0, stream>>>(
      x, selw, constw, out);
}

// Round 4
// 434.537 us; speedup vs baseline: 1.3130x; 1.3130x over previous
//
#include <hip/hip_runtime.h>

// SwitchboxElement: B=65536 rows, S=10 stages, L=1023 inputs/row.
// JAX threefry, partitionable semantics (verified passing round 2):
//   split(key,n)[i] = both words of threefry2x32(key, 0, i)
//   random_bits32(key, f) = out0 ^ out1 of threefry2x32(key, 0, f)
// Restructure (round 4, de-risked round 3): all 1024 noise draws/row packed
// into 16 FULL wave-iterations (stage 0 fused with mux + global pair reads;
// stages 1-3 stored to LDS in 7 iters; stages 4-9 packed into ONE iter with
// inline per-lane key computation — NO LDS key table, NO sqrt builtin).
// erfinv cheapened: log1p-refinement division dropped, p_big branch
// exec-mask-skipped (accuracy budget: threshold 2.97e-3, round-2 absmax 1.5e-5).

#define NROWS 65536
#define WPB 4   // waves per block (256 threads)

struct U2 { unsigned x, y; };

__host__ __device__ constexpr unsigned rotl32(unsigned v, int r) {
  return (v << r) | (v >> (32 - r));
}

// Threefry-2x32, 20 rounds, exactly JAX's schedule.
__host__ __device__ constexpr U2 threefry2x32(unsigned k0, unsigned k1,
                                              unsigned x0, unsigned x1) {
  const unsigned ks2 = k0 ^ k1 ^ 0x1BD11BDAu;
  x0 += k0; x1 += k1;
  x0 += x1; x1 = rotl32(x1, 13); x1 ^= x0;
  x0 += x1; x1 = rotl32(x1, 15); x1 ^= x0;
  x0 += x1; x1 = rotl32(x1, 26); x1 ^= x0;
  x0 += x1; x1 = rotl32(x1, 6);  x1 ^= x0;
  x0 += k1; x1 += ks2 + 1u;
  x0 += x1; x1 = rotl32(x1, 17); x1 ^= x0;
  x0 += x1; x1 = rotl32(x1, 29); x1 ^= x0;
  x0 += x1; x1 = rotl32(x1, 16); x1 ^= x0;
  x0 += x1; x1 = rotl32(x1, 24); x1 ^= x0;
  x0 += ks2; x1 += k0 + 2u;
  x0 += x1; x1 = rotl32(x1, 13); x1 ^= x0;
  x0 += x1; x1 = rotl32(x1, 15); x1 ^= x0;
  x0 += x1; x1 = rotl32(x1, 26); x1 ^= x0;
  x0 += x1; x1 = rotl32(x1, 6);  x1 ^= x0;
  x0 += k0; x1 += k1 + 3u;
  x0 += x1; x1 = rotl32(x1, 17); x1 ^= x0;
  x0 += x1; x1 = rotl32(x1, 29); x1 ^= x0;
  x0 += x1; x1 = rotl32(x1, 16); x1 ^= x0;
  x0 += x1; x1 = rotl32(x1, 24); x1 ^= x0;
  x0 += k1; x1 += ks2 + 4u;
  x0 += x1; x1 = rotl32(x1, 13); x1 ^= x0;
  x0 += x1; x1 = rotl32(x1, 15); x1 ^= x0;
  x0 += x1; x1 = rotl32(x1, 26); x1 ^= x0;
  x0 += x1; x1 = rotl32(x1, 6);  x1 ^= x0;
  x0 += ks2; x1 += k0 + 5u;
  return U2{x0, x1};
}

// keys = jax.random.split(jax.random.key(42), 11), partitionable:
// keys[i] = threefry2x32((0,42), 0, i) -> (out0, out1), no xor.
struct KeyTab { unsigned a[11]; unsigned b[11]; };
__host__ __device__ constexpr KeyTab make_keys() {
  KeyTab t{};
  for (int i = 0; i < 11; ++i) {
    U2 r = threefry2x32(0u, 42u, 0u, (unsigned)i);
    t.a[i] = r.x; t.b[i] = r.y;
  }
  return t;
}
__constant__ KeyTab g_keys = make_keys();   // proven path from round 2

__device__ inline unsigned rb32(unsigned k0, unsigned k1, unsigned f) {
  U2 r = threefry2x32(k0, k1, 0u, f);
  return r.x ^ r.y;  // partitionable 32-bit fold
}

// bits -> uniform[-1+eps,1) -> sqrt(2)*erfinv.  Cheap variant:
//  - w = -log(1-u^2): log1p refinement (an IEEE division) dropped;
//    abs n-error <= ~1e-6 — budget is ~1e-3.
//  - p_big branch (|u| > 0.99663, 0.34% of lanes) exec-mask-skipped.
__device__ inline float jax_normal_from_bits(unsigned bits) {
  const float lo = -0.99999994f;  // nextafter(-1,0); (maxval-minval) rounds to 2.0f
  float fr = __uint_as_float((bits >> 9) | 0x3F800000u) - 1.0f;  // [0,1)
  float u = fmaxf(lo, fmaf(fr, 2.0f, lo));
  float wv = -__logf(fmaf(-u, u, 1.0f));   // 1-u^2 >= 1.19e-7 > 0
  float p;
  if (wv < 5.0f) {
    float w = wv - 2.5f;
    p = 2.81022636e-08f;
    p = fmaf(p, w, 3.43273939e-07f);
    p = fmaf(p, w, -3.5233877e-06f);
    p = fmaf(p, w, -4.39150654e-06f);
    p = fmaf(p, w, 0.00021858087f);
    p = fmaf(p, w, -0.00125372503f);
    p = fmaf(p, w, -0.00417768164f);
    p = fmaf(p, w, 0.246640727f);
    p = fmaf(p, w, 1.50140941f);
  } else {
    float w = sqrtf(wv) - 3.0f;
    p = -0.000200214257f;
    p = fmaf(p, w, 0.000100950558f);
    p = fmaf(p, w, 0.00134934322f);
    p = fmaf(p, w, -0.00367342844f);
    p = fmaf(p, w, 0.00573950773f);
    p = fmaf(p, w, -0.0076224613f);
    p = fmaf(p, w, 0.00943887047f);
    p = fmaf(p, w, 1.00167406f);
    p = fmaf(p, w, 2.83297682f);
  }
  return 1.41421356f * (p * u);
}

__global__ __launch_bounds__(64 * WPB) void switchbox_kernel(
    const float* __restrict__ x,
    const float* __restrict__ selw,
    const float* __restrict__ constw,
    float* __restrict__ out) {
  // per-row: vb[512] = live tree values, sb[511] = raw normals stages 1..9
  __shared__ __align__(16) float vbuf[WPB][512];
  __shared__ __align__(16) float sbuf[WPB][512];
  const int w = threadIdx.x >> 6;
  const int lane = threadIdx.x & 63;
  const int row = blockIdx.x * WPB + w;

  float* vb = vbuf[w];
  float* sb = sbuf[w];
  const float* xr = x + (size_t)row * 1023;

  // trained-const draw (keys[10], flat idx = row) — all lanes redundantly
  float cval;
  {
    float cw = constw[0];
    float om = 1.0f - fabsf(cw);
    float n = jax_normal_from_bits(rb32(g_keys.a[10], g_keys.b[10], (unsigned)row));
    cval = cw + om * om * n * 0.125f;   // ref assoc: ((om^2)*n)*scale
  }

  // ---- stage 0 fused: 8 full iters, pairs straight from global ----
  {
    float pw = selw[0];
    float om = 1.0f - fabsf(pw);
    float om2 = om * om;
    unsigned ka = g_keys.a[0], kb = g_keys.b[0];
#pragma unroll
    for (int it = 0; it < 8; ++it) {
      int j = it * 64 + lane;
      unsigned f = ((unsigned)row << 9) + (unsigned)j;
      float n = jax_normal_from_bits(rb32(ka, kb, f));
      float s = pw + om2 * n * 0.125f;
      float av, bv;
      if (j < 511) { av = xr[2 * j]; bv = xr[2 * j + 1]; }
      else         { av = xr[1022];  bv = cval; }           // b[511] = const
      vb[j] = 0.5f * (s * av - s * bv + av + bv);           // ref op order
    }
  }

  // ---- noise for stages 1..3: 7 full iters, wave-uniform sel ----
  {
    int base = 0;
#pragma unroll
    for (int sel = 1; sel <= 3; ++sel) {
      const unsigned ka = g_keys.a[sel], kb = g_keys.b[sel];
      const int M = 512 >> sel;
      for (int j0 = 0; j0 < M; j0 += 64) {
        int j = j0 + lane;
        unsigned f = ((unsigned)row << (9 - sel)) + (unsigned)j;
        sb[base + j] = jax_normal_from_bits(rb32(ka, kb, f));
      }
      base += M;
    }
  }

  // ---- noise for stages 4..9: ONE packed iter (lanes 0..62) ----
  // stage sel occupies lanes [64 - 2^(10-sel), 64 - 2^(9-sel)); slot 448+lane.
  // Per-lane key computed inline (one extra vectorized threefry — no LDS table).
  if (lane < 63) {
    int m = 63 - lane;                 // >= 1
    int sel = 9 - (31 - __clz(m));     // 4..9
    int j = lane - 64 + (1024 >> sel); // index within stage
    U2 kk = threefry2x32(0u, 42u, 0u, (unsigned)sel);
    unsigned f = ((unsigned)row << (9 - sel)) + (unsigned)j;
    sb[448 + lane] = jax_normal_from_bits(rb32(kk.x, kk.y, f));
  }

  // ---- cheap LDS tree, stages 1..9 (in-place, wave-private) ----
  {
    int base = 0;
#pragma unroll
    for (int sel = 1; sel <= 9; ++sel) {
      const int M = 512 >> sel;
      float pw = selw[sel];
      float om = 1.0f - fabsf(pw);
      float om2 = om * om;
      for (int j = lane; j < M; j += 64) {
        float n = sb[base + j];
        float s = pw + om2 * n * 0.125f;
        float2 ab = *(const float2*)&vb[2 * j];  // ds_read_b64, 2-way = free
        float av = ab.x, bv = ab.y;
        vb[j] = 0.5f * (s * av - s * bv + av + bv);
      }
      base += M;
      // no barrier: wave-private region; reads precede overlapping writes
      // in wave program order; cross-iteration ranges disjoint.
    }
  }

  if (lane == 0) out[row] = vb[0];
}

extern "C" void kernel_launch(void* const* d_in, const int* in_sizes, int n_in,
                              void* d_out, int out_size, void* d_ws, size_t ws_size,
                              hipStream_t stream) {
  (void)in_sizes; (void)n_in; (void)d_ws; (void)ws_size; (void)out_size;
  const float* x      = (const float*)d_in[0];
  const float* selw   = (const float*)d_in[1];
  const float* constw = (const float*)d_in[2];
  float* out = (float*)d_out;
  switchbox_kernel<<<dim3(NROWS / WPB), dim3(64 * WPB), 0, stream>>>(
      x, selw, constw, out);
}

// Round 5
// 413.873 us; speedup vs baseline: 1.3785x; 1.0499x over previous
//
#include <hip/hip_runtime.h>

// SwitchboxElement: B=65536 rows, S=10 stages, L=1023 inputs/row.
// JAX threefry, partitionable semantics (verified rounds 2 & 4):
//   split(key,n)[i] = both words of threefry2x32(key, 0, i)
//   random_bits32(key, f) = out0 ^ out1 of threefry2x32(key, 0, f)
// Round 5: instruction-fat removal on the verified round-4 structure.
//  - rotates forced to v_alignbit_b32 (device path; constexpr path keeps
//    shift-or for the compile-time key tables)
//  - stages 1-3 noise FUSED with their mux (no LDS round-trip, no 2nd pass)
//  - stages 4-9 packed iter keys/shift/offset from a __constant__ lane table
//    (one dwordx4 load replaces an inline ~71-op threefry)
//  - trained-const draw scalarized via readfirstlane (scalar pipe, free)
//  - fmax dropped (no-op: fma(fr,2,lo) >= lo), -log fold into log2 constant
// Accuracy budget: threshold 2.97e-3; rounds 2/4 absmax 1.5e-5.

#define NROWS 65536
#define WPB 4   // waves per block (256 threads)

struct U2 { unsigned x, y; };

// ---------- constexpr (host/compile-time) threefry for key tables ----------
__host__ __device__ constexpr unsigned rotl_c(unsigned v, int r) {
  return (v << r) | (v >> (32 - r));
}
__host__ __device__ constexpr U2 threefry_c(unsigned k0, unsigned k1,
                                            unsigned x0, unsigned x1) {
  const unsigned ks2 = k0 ^ k1 ^ 0x1BD11BDAu;
  x0 += k0; x1 += k1;
  x0 += x1; x1 = rotl_c(x1, 13); x1 ^= x0;
  x0 += x1; x1 = rotl_c(x1, 15); x1 ^= x0;
  x0 += x1; x1 = rotl_c(x1, 26); x1 ^= x0;
  x0 += x1; x1 = rotl_c(x1, 6);  x1 ^= x0;
  x0 += k1; x1 += ks2 + 1u;
  x0 += x1; x1 = rotl_c(x1, 17); x1 ^= x0;
  x0 += x1; x1 = rotl_c(x1, 29); x1 ^= x0;
  x0 += x1; x1 = rotl_c(x1, 16); x1 ^= x0;
  x0 += x1; x1 = rotl_c(x1, 24); x1 ^= x0;
  x0 += ks2; x1 += k0 + 2u;
  x0 += x1; x1 = rotl_c(x1, 13); x1 ^= x0;
  x0 += x1; x1 = rotl_c(x1, 15); x1 ^= x0;
  x0 += x1; x1 = rotl_c(x1, 26); x1 ^= x0;
  x0 += x1; x1 = rotl_c(x1, 6);  x1 ^= x0;
  x0 += k0; x1 += k1 + 3u;
  x0 += x1; x1 = rotl_c(x1, 17); x1 ^= x0;
  x0 += x1; x1 = rotl_c(x1, 29); x1 ^= x0;
  x0 += x1; x1 = rotl_c(x1, 16); x1 ^= x0;
  x0 += x1; x1 = rotl_c(x1, 24); x1 ^= x0;
  x0 += k1; x1 += ks2 + 4u;
  x0 += x1; x1 = rotl_c(x1, 13); x1 ^= x0;
  x0 += x1; x1 = rotl_c(x1, 15); x1 ^= x0;
  x0 += x1; x1 = rotl_c(x1, 26); x1 ^= x0;
  x0 += x1; x1 = rotl_c(x1, 6);  x1 ^= x0;
  x0 += ks2; x1 += k0 + 5u;
  return U2{x0, x1};
}

// ---------- device threefry with guaranteed v_alignbit rotates ----------
__device__ __forceinline__ unsigned rotl_d(unsigned v, int r) {
  return __builtin_amdgcn_alignbit(v, v, 32 - r);  // (v<<r)|(v>>(32-r))
}
__device__ __forceinline__ U2 threefry_d(unsigned k0, unsigned k1,
                                         unsigned x0, unsigned x1) {
  const unsigned ks2 = k0 ^ k1 ^ 0x1BD11BDAu;
  x0 += k0; x1 += k1;
  x0 += x1; x1 = rotl_d(x1, 13); x1 ^= x0;
  x0 += x1; x1 = rotl_d(x1, 15); x1 ^= x0;
  x0 += x1; x1 = rotl_d(x1, 26); x1 ^= x0;
  x0 += x1; x1 = rotl_d(x1, 6);  x1 ^= x0;
  x0 += k1; x1 += ks2 + 1u;
  x0 += x1; x1 = rotl_d(x1, 17); x1 ^= x0;
  x0 += x1; x1 = rotl_d(x1, 29); x1 ^= x0;
  x0 += x1; x1 = rotl_d(x1, 16); x1 ^= x0;
  x0 += x1; x1 = rotl_d(x1, 24); x1 ^= x0;
  x0 += ks2; x1 += k0 + 2u;
  x0 += x1; x1 = rotl_d(x1, 13); x1 ^= x0;
  x0 += x1; x1 = rotl_d(x1, 15); x1 ^= x0;
  x0 += x1; x1 = rotl_d(x1, 26); x1 ^= x0;
  x0 += x1; x1 = rotl_d(x1, 6);  x1 ^= x0;
  x0 += k0; x1 += k1 + 3u;
  x0 += x1; x1 = rotl_d(x1, 17); x1 ^= x0;
  x0 += x1; x1 = rotl_d(x1, 29); x1 ^= x0;
  x0 += x1; x1 = rotl_d(x1, 16); x1 ^= x0;
  x0 += x1; x1 = rotl_d(x1, 24); x1 ^= x0;
  x0 += k1; x1 += ks2 + 4u;
  x0 += x1; x1 = rotl_d(x1, 13); x1 ^= x0;
  x0 += x1; x1 = rotl_d(x1, 15); x1 ^= x0;
  x0 += x1; x1 = rotl_d(x1, 26); x1 ^= x0;
  x0 += x1; x1 = rotl_d(x1, 6);  x1 ^= x0;
  x0 += ks2; x1 += k0 + 5u;
  return U2{x0, x1};
}
__device__ __forceinline__ unsigned rb32(unsigned k0, unsigned k1, unsigned f) {
  U2 r = threefry_d(k0, k1, 0u, f);
  return r.x ^ r.y;  // partitionable 32-bit fold
}

// keys = jax.random.split(jax.random.key(42), 11)
struct KeyTab { unsigned a[11]; unsigned b[11]; };
__host__ __device__ constexpr KeyTab make_keys() {
  KeyTab t{};
  for (int i = 0; i < 11; ++i) {
    U2 r = threefry_c(0u, 42u, 0u, (unsigned)i);
    t.a[i] = r.x; t.b[i] = r.y;
  }
  return t;
}
__constant__ KeyTab g_keys = make_keys();

// Per-lane table for the packed stages-4..9 draw iteration.
// lane l (0..62): m=63-l, sel = 9 - floor(log2(m)) in [4,9],
// j = l - 64 + 2^(10-sel), f = (row << (9-sel)) + j, key = keys[sel].
struct __align__(16) PKe { unsigned a, b, sh, jo; };
struct PKTab { PKe e[64]; };
__host__ __device__ constexpr PKTab make_pk() {
  PKTab t{};
  for (int lane = 0; lane < 63; ++lane) {
    int m = 63 - lane;
    int lg = 0;
    while ((1 << (lg + 1)) <= m) ++lg;   // floor(log2(m))
    int sel = 9 - lg;                    // 4..9
    int j = lane - 64 + (1024 >> sel);
    U2 r = threefry_c(0u, 42u, 0u, (unsigned)sel);
    t.e[lane].a = r.x; t.e[lane].b = r.y;
    t.e[lane].sh = (unsigned)(9 - sel);
    t.e[lane].jo = (unsigned)j;
  }
  t.e[63].a = 0; t.e[63].b = 0; t.e[63].sh = 0; t.e[63].jo = 0;
  return t;
}
__constant__ PKTab g_pk = make_pk();

// bits -> uniform[-1+eps,1) -> sqrt(2)*erfinv (Giles float poly, XLA-style).
// Cheap variant (verified round 4, absmax 1.5e-5): no log1p-refine division,
// p_big branch exec-mask-skipped. fmax dropped: fma(fr,2,lo) >= lo by RNE
// monotonicity. -log folded into the log2 constant (bit-identical, RNE sign
// symmetry).
__device__ __forceinline__ float jax_normal_from_bits(unsigned bits) {
  const float lo = -0.99999994f;  // nextafter(-1,0); (maxval-minval) -> 2.0f
  float fr = __uint_as_float((bits >> 9) | 0x3F800000u) - 1.0f;  // [0,1)
  float u = fmaf(fr, 2.0f, lo);
  float wv = __log2f(fmaf(-u, u, 1.0f)) * -0.69314718f;  // -ln(1-u^2)
  float p;
  if (wv < 5.0f) {
    float w = wv - 2.5f;
    p = 2.81022636e-08f;
    p = fmaf(p, w, 3.43273939e-07f);
    p = fmaf(p, w, -3.5233877e-06f);
    p = fmaf(p, w, -4.39150654e-06f);
    p = fmaf(p, w, 0.00021858087f);
    p = fmaf(p, w, -0.00125372503f);
    p = fmaf(p, w, -0.00417768164f);
    p = fmaf(p, w, 0.246640727f);
    p = fmaf(p, w, 1.50140941f);
  } else {
    float w = sqrtf(wv) - 3.0f;
    p = -0.000200214257f;
    p = fmaf(p, w, 0.000100950558f);
    p = fmaf(p, w, 0.00134934322f);
    p = fmaf(p, w, -0.00367342844f);
    p = fmaf(p, w, 0.00573950773f);
    p = fmaf(p, w, -0.0076224613f);
    p = fmaf(p, w, 0.00943887047f);
    p = fmaf(p, w, 1.00167406f);
    p = fmaf(p, w, 2.83297682f);
  }
  return 1.41421356f * (p * u);
}

__global__ __launch_bounds__(64 * WPB) void switchbox_kernel(
    const float* __restrict__ x,
    const float* __restrict__ selw,
    const float* __restrict__ constw,
    float* __restrict__ out) {
  __shared__ __align__(16) float vbuf[WPB][512];  // live tree values
  __shared__ __align__(16) float sbuf[WPB][64];   // stages 4-9 normals
  const int w = threadIdx.x >> 6;
  const int lane = threadIdx.x & 63;
  const int row = blockIdx.x * WPB + w;

  float* vb = vbuf[w];
  float* sb = sbuf[w];
  const float* xr = x + (size_t)row * 1023;

  // trained-const draw (keys[10], flat idx = row): row is wave-uniform;
  // readfirstlane routes the ~70-op threefry to the scalar pipe.
  float cval;
  {
    unsigned row_u = (unsigned)__builtin_amdgcn_readfirstlane(row);
    float cw = constw[0];
    float om = 1.0f - fabsf(cw);
    float n = jax_normal_from_bits(rb32(g_keys.a[10], g_keys.b[10], row_u));
    cval = cw + om * om * n * 0.125f;   // ref assoc: ((om^2)*n)*scale
  }

  // ---- stage 0 fused: 8 full iters, pairs straight from global ----
  {
    float pw = selw[0];
    float om = 1.0f - fabsf(pw);
    float om2 = om * om;
    unsigned ka = g_keys.a[0], kb = g_keys.b[0];
#pragma unroll
    for (int it = 0; it < 8; ++it) {
      int j = it * 64 + lane;
      unsigned f = ((unsigned)row << 9) + (unsigned)j;
      float n = jax_normal_from_bits(rb32(ka, kb, f));
      float s = pw + om2 * n * 0.125f;
      float av, bv;
      if (j < 511) { av = xr[2 * j]; bv = xr[2 * j + 1]; }
      else         { av = xr[1022];  bv = cval; }           // b[511] = const
      vb[j] = 0.5f * (s * av - s * bv + av + bv);           // ref op order
    }
  }

  // ---- stages 1..3: noise FUSED with mux (no LDS round-trip) ----
  // Safety (in-place, wave-private): iter k reads vb[128k,128k+128), writes
  // vb[64k,64k+64); all prior writes end at 64k+64 <= 128k for k>=1, and the
  // wave's ds_reads of an iteration issue before its ds_writes (program
  // order), so k=0 overlap is read-before-write. Proven pattern (rounds 2/4).
#pragma unroll
  for (int sel = 1; sel <= 3; ++sel) {
    const int M = 512 >> sel;
    const unsigned ka = g_keys.a[sel], kb = g_keys.b[sel];
    float pw = selw[sel];
    float om = 1.0f - fabsf(pw);
    float om2 = om * om;
#pragma unroll
    for (int j0 = 0; j0 < M; j0 += 64) {
      int j = j0 + lane;
      unsigned f = ((unsigned)row << (9 - sel)) + (unsigned)j;
      float n = jax_normal_from_bits(rb32(ka, kb, f));
      float s = pw + om2 * n * 0.125f;
      float2 ab = *(const float2*)&vb[2 * j];   // ds_read_b64, 2-way = free
      float av = ab.x, bv = ab.y;
      vb[j] = 0.5f * (s * av - s * bv + av + bv);
    }
  }

  // ---- noise for stages 4..9: ONE packed iter, lane table from constmem ----
  if (lane < 63) {
    PKe k = g_pk.e[lane];                 // one dwordx4 load
    unsigned f = ((unsigned)row << k.sh) + k.jo;
    sb[lane] = jax_normal_from_bits(rb32(k.a, k.b, f));
  }

  // ---- tree stages 4..9 (cheap, <=32 active lanes) ----
#pragma unroll
  for (int sel = 4; sel <= 9; ++sel) {
    const int M = 512 >> sel;             // 32..1
    float pw = selw[sel];
    float om = 1.0f - fabsf(pw);
    float om2 = om * om;
    if (lane < M) {
      int j = lane;
      float n = sb[64 - (1024 >> sel) + j];   // slot written by packed iter
      float s = pw + om2 * n * 0.125f;
      float2 ab = *(const float2*)&vb[2 * j];
      float av = ab.x, bv = ab.y;
      vb[j] = 0.5f * (s * av - s * bv + av + bv);
    }
  }

  if (lane == 0) out[row] = vb[0];
}

extern "C" void kernel_launch(void* const* d_in, const int* in_sizes, int n_in,
                              void* d_out, int out_size, void* d_ws, size_t ws_size,
                              hipStream_t stream) {
  (void)in_sizes; (void)n_in; (void)d_ws; (void)ws_size; (void)out_size;
  const float* x      = (const float*)d_in[0];
  const float* selw   = (const float*)d_in[1];
  const float* constw = (const float*)d_in[2];
  float* out = (float*)d_out;
  switchbox_kernel<<<dim3(NROWS / WPB), dim3(64 * WPB), 0, stream>>>(
      x, selw, constw, out);
}